// Round 10
// baseline (148.117 us; speedup 1.0000x reference)
//
#include <hip/hip_runtime.h>
#include <hip/hip_bf16.h>
#include <math.h>

#define NPTS 100000
#define NSTRIPE 1568     // 64-row stripes; 196 per XCD
#define KCOMP 64

typedef float v4f __attribute__((ext_vector_type(4)));
typedef __bf16 v8bf __attribute__((ext_vector_type(8)));
typedef __bf16 v4bf __attribute__((ext_vector_type(4)));

// Fragment-native layouts (NO LDS, NO barriers in the GEMM):
//   Xb[st(1568)][ks(8)][m(4)][lane(64)][e(8)] : X[st*64 + m*16 + (l&15)][ks*32 + (l>>4)*8 + e]
//   Bt[cw(16)][ks(8)][n(4)][lane(64)][e(8)]   : B[cw*64 + n*16 + (l&15)][ks*32 + (l>>4)*8 + e]
// Every fragment load = one coalesced global_load_dwordx4 (base + lane*16).

// ---------- kernel 1: per-component prep (Cholesky of I+M^T M, B = L^-1 M^T) ----------
__global__ __launch_bounds__(256) void prep_comp(const float* __restrict__ M,
                                                 const float* __restrict__ pi,
                                                 __bf16* __restrict__ Bt,
                                                 float* __restrict__ cvec,
                                                 float logSA) {
    __shared__ float Ml[256][16];
    __shared__ float S[16][17];
    __shared__ float sh_logpi;
    const int k = blockIdx.x, t = threadIdx.x;

    const float4* src = (const float4*)(M + (size_t)k * 4096 + (size_t)t * 16);
    float4 a0 = src[0], a1 = src[1], a2 = src[2], a3 = src[3];
    ((float4*)Ml[t])[0] = a0; ((float4*)Ml[t])[1] = a1;
    ((float4*)Ml[t])[2] = a2; ((float4*)Ml[t])[3] = a3;

    if (t < 64) {
        float v = pi[t];
        float mx = v;
        for (int off = 32; off; off >>= 1) mx = fmaxf(mx, __shfl_xor(mx, off));
        float e = __expf(v - mx);
        float s = e;
        for (int off = 32; off; off >>= 1) s += __shfl_xor(s, off);
        if (t == 0) sh_logpi = pi[k] - mx - logf(s);
    }
    __syncthreads();

    {
        int r = t >> 4, c = t & 15;
        float s = (r == c) ? 1.0f : 0.0f;
        for (int p = 0; p < 256; ++p) s += Ml[p][r] * Ml[p][c];
        S[r][c] = s;
    }
    __syncthreads();

    for (int j = 0; j < 16; ++j) {
        if (t == 0) S[j][j] = sqrtf(S[j][j]);
        __syncthreads();
        if (t > j && t < 16) S[t][j] = S[t][j] / S[j][j];
        __syncthreads();
        {
            int r = t >> 4, c = t & 15;
            if (r > j && c > j && c <= r) S[r][c] -= S[r][j] * S[c][j];
        }
        __syncthreads();
    }

    if (t == 0) {
        float ldet = 0.0f;
        for (int j = 0; j < 16; ++j) ldet += logf(S[j][j]);
        cvec[k] = logSA - ldet + sh_logpi;
    }

    float m[16] = {a0.x, a0.y, a0.z, a0.w, a1.x, a1.y, a1.z, a1.w,
                   a2.x, a2.y, a2.z, a2.w, a3.x, a3.y, a3.z, a3.w};
    float y[16];
#pragma unroll
    for (int r = 0; r < 16; ++r) {
        float v = m[r];
#pragma unroll
        for (int q = 0; q < r; ++q) v -= S[r][q] * y[q];
        y[r] = v / S[r][r];
    }
    // fragment-native Bt write: cw=k>>2, n=k&3, lane=((t>>3)&3)*16+r, ks=t>>5, e=t&7
    const int cw = k >> 2, n = k & 3;
    const int ks = t >> 5, e = t & 7;
    const int lbase = ((t >> 3) & 3) * 16;
#pragma unroll
    for (int r = 0; r < 16; ++r) {
        const size_t off = (size_t)cw * 16384 + (size_t)ks * 2048 + (size_t)n * 512
                         + (size_t)(lbase + r) * 8 + e;
        Bt[off] = (__bf16)y[r];
    }
}

// ---------- kernel 2: X fp32 -> bf16 into fragment-native stripes ----------
__global__ __launch_bounds__(256) void convert_X(const float* __restrict__ X,
                                                 __bf16* __restrict__ Xb) {
    __shared__ __bf16 T[64][264];
    const int st = blockIdx.x;
    const int n0 = st * 64;
    const int t = threadIdx.x;

#pragma unroll
    for (int j = 0; j < 16; ++j) {
        const int u = j * 256 + t;
        const int r = u >> 6, c4 = u & 63;
        const int n = n0 + r;
        float4 v = make_float4(0.f, 0.f, 0.f, 0.f);
        if (n < NPTS) v = ((const float4*)X)[(size_t)n * 64 + c4];
        v4bf o = {(__bf16)v.x, (__bf16)v.y, (__bf16)v.z, (__bf16)v.w};
        *(v4bf*)&T[r][c4 * 4] = o;
    }
    __syncthreads();

#pragma unroll
    for (int ks = 0; ks < 8; ++ks) {
        const int mh = t >> 6;
        const int l = t & 63;
        const int row = mh * 16 + (l & 15);
        const int col = ks * 32 + (l >> 4) * 8;
        v8bf val = *(const v8bf*)&T[row][col];
        const size_t off = (size_t)st * 16384 + (size_t)ks * 2048
                         + (size_t)mh * 512 + (size_t)l * 8;
        *(v8bf*)(Xb + off) = val;
    }
}

// ---------- kernel 3: barrier-free GEMM + fused density + ONLINE LOGSUMEXP ----------
// Wave owns a 64-row stripe: A fragments pinned in 128 VGPRs (loaded once);
// B double-buffer-prefetched from L2; epilogue keeps online-LSE state per m-tile;
// one atomicAdd per wave. No dens buffer, no reduce kernel.
__global__ __launch_bounds__(256, 2) void gemm_density(const __bf16* __restrict__ Xb,
                                                       const __bf16* __restrict__ Bt,
                                                       const float* __restrict__ cvec,
                                                       float* __restrict__ out) {
    const int bid = blockIdx.x;
    const int xcd = bid & 7;
    const int w = threadIdx.x >> 6, lane = threadIdx.x & 63;
    const int widx = (bid >> 3) * 4 + w;
    if (widx >= 196) return;
    const int st = xcd * 196 + widx;
    const int laneoff = lane * 8;

    // ---- load + PIN all A fragments (32 x dwordx4 = 128 VGPR) ----
    const __bf16* Ab = Xb + ((size_t)st << 14) + laneoff;
    v8bf af[8][4];
#pragma unroll
    for (int ks = 0; ks < 8; ++ks)
#pragma unroll
        for (int m = 0; m < 4; ++m) {
            af[ks][m] = *(const v8bf*)(Ab + ks * 2048 + m * 512);
            asm volatile("" : "+v"(af[ks][m]));   // forbid rematerialization
        }

    const __bf16* Bbase = Bt + laneoff;
#define LOADB(dst, cw_, ks_) do {                                                \
    const __bf16* _p = Bbase + ((size_t)(cw_) << 14) + (ks_) * 2048;             \
    _Pragma("unroll")                                                            \
    for (int n = 0; n < 4; ++n) dst[n] = *(const v8bf*)(_p + n * 512);           \
} while (0)
#define MFMA16(bg, ks) do {                                                      \
    _Pragma("unroll")                                                            \
    for (int m = 0; m < 4; ++m)                                                  \
        _Pragma("unroll")                                                        \
        for (int n = 0; n < 4; ++n)                                              \
            acc[m][n] = __builtin_amdgcn_mfma_f32_16x16x32_bf16(bg[n], af[ks][m], acc[m][n], 0, 0, 0); \
} while (0)

    const float4* cv4 = (const float4*)cvec;
    const v4f z4 = (v4f)(0.0f);

    v8bf bgA[4], bgB[4];
    LOADB(bgA, 0, 0);

    float mrun[4] = {-INFINITY, -INFINITY, -INFINITY, -INFINITY};
    float srun[4] = {0.f, 0.f, 0.f, 0.f};

#pragma unroll 1
    for (int cw = 0; cw < 16; ++cw) {
        v4f acc[4][4];
        // group 0 (bgA): init accumulators via C=0
        LOADB(bgB, cw, 1);
#pragma unroll
        for (int m = 0; m < 4; ++m)
#pragma unroll
            for (int n = 0; n < 4; ++n)
                acc[m][n] = __builtin_amdgcn_mfma_f32_16x16x32_bf16(bgB[n] * (__bf16)0.f + bgA[n], af[0][m], z4, 0, 0, 0);
        // ^ NOTE: bgB[n]*0+bgA[n] is just bgA[n]; keeps bgB's load from being sunk.
        LOADB(bgA, cw, 2);
        MFMA16(bgB, 1);
#pragma unroll
        for (int kp = 1; kp < 4; ++kp) {
            const int k0 = kp * 2, k1 = kp * 2 + 1;
            LOADB(bgB, cw, k1);
            MFMA16(bgA, k0);
            if (k1 < 7) { LOADB(bgA, cw, k1 + 1); }
            else if (cw < 15) { LOADB(bgA, cw + 1, 0); }
            MFMA16(bgB, k1);
        }

        // ---- epilogue: quad -> density -> online LSE (all lanes) ----
        const float4 cv = cv4[cw];
#pragma unroll
        for (int m = 0; m < 4; ++m) {
            float d[4];
#pragma unroll
            for (int n = 0; n < 4; ++n) {
                v4f qv = acc[m][n];
                float s = qv[0] * qv[0] + qv[1] * qv[1] + qv[2] * qv[2] + qv[3] * qv[3];
                s += __shfl_xor(s, 16);
                s += __shfl_xor(s, 32);
                const float c = (n == 0) ? cv.x : (n == 1) ? cv.y : (n == 2) ? cv.z : cv.w;
                d[n] = c - 128.0f * __logf(1.0f - s);
            }
            const float mt = fmaxf(fmaxf(d[0], d[1]), fmaxf(d[2], d[3]));
            const float mn = fmaxf(mrun[m], mt);
            srun[m] = srun[m] * __expf(mrun[m] - mn)
                    + __expf(d[0] - mn) + __expf(d[1] - mn)
                    + __expf(d[2] - mn) + __expf(d[3] - mn);
            mrun[m] = mn;
        }
    }
#undef LOADB
#undef MFMA16

    // ---- final: per-point LSE, mask pad points, wave-sum, one atomic ----
    float tot = 0.f;
#pragma unroll
    for (int m = 0; m < 4; ++m) {
        const int pt = st * 64 + m * 16 + (lane & 15);
        const float lse = mrun[m] + __logf(srun[m]);
        tot += (pt < NPTS) ? lse : 0.f;
    }
    // lanes with equal (lane&15) hold duplicates; reduce within one 16-group
    tot += __shfl_xor(tot, 1);
    tot += __shfl_xor(tot, 2);
    tot += __shfl_xor(tot, 4);
    tot += __shfl_xor(tot, 8);
    if (lane == 0) atomicAdd(out, tot);
}

extern "C" void kernel_launch(void* const* d_in, const int* in_sizes, int n_in,
                              void* d_out, int out_size, void* d_ws, size_t ws_size,
                              hipStream_t stream) {
    const float* X  = (const float*)d_in[0];
    const float* M  = (const float*)d_in[1];
    const float* pi = (const float*)d_in[2];
    float* out = (float*)d_out;

    char* ws = (char*)d_ws;
    __bf16* Xb   = (__bf16*)ws;                           // 1568*16384*2 = 51,380,224
    __bf16* Bt   = (__bf16*)(ws + 51380224);              // 16*16384*2   =    524,288
    float*  cvec = (float*)(ws + 51904512);               // 256 B

    const double half_p = 128.0;
    const float logSA = (float)(lgamma(half_p) - log(2.0) - half_p * log(M_PI));

    hipMemsetAsync(d_out, 0, sizeof(float), stream);
    prep_comp<<<64, 256, 0, stream>>>(M, pi, Bt, cvec, logSA);
    convert_X<<<1568, 256, 0, stream>>>(X, Xb);
    gemm_density<<<512, 256, 0, stream>>>(Xb, Bt, cvec, out);
}